// Round 12
// baseline (367.350 us; speedup 1.0000x reference)
//
#include <hip/hip_runtime.h>

// ViewMorphing forward — MI355X (gfx950)
// out[0 .. 3*N*HW-1] = warped+masked image sum, out[3*N*HW] = oob loss scalar.
//
// v11: unconfound v10. v10's launch_bounds(256,4) only sets MIN waves/EU;
//      allocator still chased the 8-waves/64-VGPR bucket and spilled
//      (WRITE 98.5->180MB, dur 134->150). Two fixes:
//  1. amdgpu_waves_per_eu(4,4): pin exactly 4 waves/EU (= what the 40KB LDS
//     allows anyway) -> 128-VGPR budget, no spill incentive.
//  2. register diet: baseA/B + inA/B derived from offA/B at use
//     (rel = off - (wlo<<9); in = (unsigned)rel < (WROWS-1)<<9;
//      ldsA = rel, ldsB = PLANE + rel) -> ~16 fewer live VGPRs.
//  - keeps v10: 10-row window (kills in-phase global-fallback tails),
//    float2/ds_read2 tap pairs (halve DS instrs), channel phasing, T14
//    prefetch, stride-512, consecutive-pixel mapping, XCD slab swizzle,
//    NT streams, exact reference math.

constexpr int D    = 512;
constexpr int HW   = D * D;            // 262144 = 2^18
constexpr int NB   = 32;
constexpr int NPIX = NB * HW;          // 8,388,608
// loss scale: 0.01 / (N*2*HW) / (D*D)
constexpr float LOSS_SCALE = (float)(0.01 / (2.0 * (double)NPIX * (double)HW));

typedef float f4 __attribute__((ext_vector_type(4)));

constexpr int WROWS   = 10;                // rows [r-4, r+5]
constexpr int RSTRIDE = 512;               // = 0 mod 32: bank = col mod 32
constexpr int PLANE   = WROWS * RSTRIDE;   // 5120 floats per image-channel
constexpr int LDSZ    = 2 * PLANE;         // 40,960 B exactly -> 4 blocks/CU
constexpr int INLIM   = (WROWS - 1) << 9;  // in-window: rel in [0, INLIM)

__device__ __forceinline__ float lerp2(float v00, float v01, float v10, float v11,
                                       float ax, float ay)
{
    float top = fmaf(ay, v01 - v00, v00);
    float bot = fmaf(ay, v11 - v10, v10);
    return fmaf(ax, bot - top, top);
}

__global__ void __launch_bounds__(256)
__attribute__((amdgpu_waves_per_eu(4, 4)))
vm_fwd(const float* __restrict__ im1, const float* __restrict__ im2,
       const float* __restrict__ C,   const float* __restrict__ M1,
       const float* __restrict__ M2,  float* __restrict__ out)
{
    __shared__ float lds[LDSZ];

    // XCD slab swizzle (bijective: 8192 = 8*1024): XCD x owns 4 whole images.
    const int b    = blockIdx.x;
    const int slab = ((b & 7) << 10) | (b >> 3);

    const int n   = slab >> 8;
    const int k   = slab & 255;                 // row-pair index within image
    const int r   = k << 1;                     // first owned pixel row
    const int tid = threadIdx.x;
    const int hw0 = (k << 10) | tid;
    const int wlo = min(max(r - 4, 0), D - WROWS);   // staged-window first row
    const int wbase = wlo << 9;

    const float* Cn = C   + (size_t)n * 2 * HW;
    const float* Mp = M1  + (size_t)n * HW;
    const float* Mq = M2  + (size_t)n * HW;
    const float* p1 = im1 + (size_t)n * 3 * HW;
    const float* p2 = im2 + (size_t)n * 3 * HW;
    float* op       = out + (size_t)n * 3 * HW;

    // ---- staging helpers: 10 f4/thread/phase (2 img x 10 rows x 512 cols)
    // q=0..9 compile-time: img = q>=5, u = (q%5)*2 + su
    const int su  = (tid >> 7);                 // 0 or 1
    const int sc4 = (tid & 127) << 2;           // col

    f4 pf[10];
    #define PFLOAD(CH)                                                          \
        _Pragma("unroll")                                                       \
        for (int q = 0; q < 10; ++q) {                                          \
            const float* ip = (q < 5) ? p1 : p2;                                \
            int u = (q % 5) * 2 + su;                                           \
            pf[q] = *(const f4*)(ip + (size_t)(CH) * HW + ((wlo + u) << 9) + sc4); \
        }
    #define PFWRITE()                                                           \
        _Pragma("unroll")                                                       \
        for (int q = 0; q < 10; ++q) {                                          \
            int u = (q % 5) * 2 + su;                                           \
            int img = (q < 5) ? 0 : 1;                                          \
            *(f4*)(lds + img * PLANE + u * RSTRIDE + sc4) = pf[q];              \
        }

    PFLOAD(0);                                  // overlaps coord math below

    // ---- coord precompute (once; reused across 3 channel phases) ----
    // live state per px: axA,ayA,w1v,offA + axB,ayB,w2v,offB  (32 VGPR)
    float oob = 0.0f;
    float axA[4], ayA[4], w1v[4], axB[4], ayB[4], w2v[4];
    int   offA[4], offB[4];

    #pragma unroll
    for (int j = 0; j < 4; ++j) {
        const int hw = hw0 + j * 256;
        const float qx = (float)(hw >> 9);
        const float qy = (float)(hw & 511);
        float c0 = __builtin_nontemporal_load(Cn + hw);
        float c1 = __builtin_nontemporal_load(Cn + HW + hw);
        float m1 = __builtin_nontemporal_load(Mp + hw);
        float m2 = __builtin_nontemporal_load(Mq + hw);

        const float hi = 510.999f;              // D - 1.001
        // --- A: im1 at q + c ---
        {
            float q0o = qx + c0, q1o = qy + c1;
            float q0 = fminf(fmaxf(q0o, 0.001f), hi);
            float q1 = fminf(fmaxf(q1o, 0.001f), hi);
            float d0 = q0o - q0, d1 = q1o - q1;
            oob = fmaf(d0, d0, oob); oob = fmaf(d1, d1, oob);
            float fx = floorf(q0), fy = floorf(q1);
            axA[j] = q0 - fx; ayA[j] = q1 - fy;
            // reference ceil==floor case: coincident taps, weights sum to 2
            float sc = ((axA[j] == 0.0f) ? 2.0f : 1.0f) * ((ayA[j] == 0.0f) ? 2.0f : 1.0f);
            w1v[j] = m1 * sc;
            offA[j] = (int)fy + (((int)fx) << 9);    // global flat (row-major)
        }
        // --- B: im2 at q - c ---
        {
            float q0o = qx - c0, q1o = qy - c1;
            float q0 = fminf(fmaxf(q0o, 0.001f), hi);
            float q1 = fminf(fmaxf(q1o, 0.001f), hi);
            float d0 = q0o - q0, d1 = q1o - q1;
            oob = fmaf(d0, d0, oob); oob = fmaf(d1, d1, oob);
            float fx = floorf(q0), fy = floorf(q1);
            axB[j] = q0 - fx; ayB[j] = q1 - fy;
            float sc = ((axB[j] == 0.0f) ? 2.0f : 1.0f) * ((ayB[j] == 0.0f) ? 2.0f : 1.0f);
            w2v[j] = m2 * sc;
            offB[j] = (int)fy + (((int)fx) << 9);
        }
    }

    #pragma unroll
    for (int ch = 0; ch < 3; ++ch) {
        PFWRITE();
        __syncthreads();                        // staged data visible; pf regs free
        if (ch < 2) PFLOAD(ch + 1);             // T14: lands under sampling below

        const float* g1 = p1 + (size_t)ch * HW; // fallback bases (SGPR)
        const float* g2 = p2 + (size_t)ch * HW;
        float* oc = op + (size_t)ch * HW;

        #pragma unroll
        for (int j = 0; j < 4; ++j) {
            float ra, rb;
            int relA = offA[j] - wbase;         // = u*512 + iy when in-window
            if ((unsigned)relA < (unsigned)INLIM) {
                float2 t0, t1;                  // adjacent cols -> ds_read2_b32
                __builtin_memcpy(&t0, &lds[relA], 8);
                __builtin_memcpy(&t1, &lds[relA + RSTRIDE], 8);
                ra = lerp2(t0.x, t0.y, t1.x, t1.y, axA[j], ayA[j]);
            } else {
                const float* pa = g1 + offA[j];
                ra = lerp2(pa[0], pa[1], pa[512], pa[513], axA[j], ayA[j]);
            }
            int relB = offB[j] - wbase;
            if ((unsigned)relB < (unsigned)INLIM) {
                float2 t0, t1;
                __builtin_memcpy(&t0, &lds[PLANE + relB], 8);
                __builtin_memcpy(&t1, &lds[PLANE + relB + RSTRIDE], 8);
                rb = lerp2(t0.x, t0.y, t1.x, t1.y, axB[j], ayB[j]);
            } else {
                const float* pb = g2 + offB[j];
                rb = lerp2(pb[0], pb[1], pb[512], pb[513], axB[j], ayB[j]);
            }
            __builtin_nontemporal_store(fmaf(ra, w1v[j], rb * w2v[j]),
                                        oc + hw0 + j * 256);
        }
        __syncthreads();                        // all reads done before next overwrite
    }

    // block-level reduction of oob; wave_sums reuses lds (post-final-barrier)
    #pragma unroll
    for (int off = 32; off > 0; off >>= 1)
        oob += __shfl_down(oob, off, 64);

    int lane = tid & 63;
    int wave = tid >> 6;
    if (lane == 0) lds[wave] = oob;
    __syncthreads();
    if (tid == 0) {
        float s = lds[0] + lds[1] + lds[2] + lds[3];
        atomicAdd(out + (size_t)3 * NPIX, s * LOSS_SCALE);
    }
}

extern "C" void kernel_launch(void* const* d_in, const int* in_sizes, int n_in,
                              void* d_out, int out_size, void* d_ws, size_t ws_size,
                              hipStream_t stream) {
    const float* im1 = (const float*)d_in[0];
    const float* im2 = (const float*)d_in[1];
    const float* C   = (const float*)d_in[2];
    const float* M1  = (const float*)d_in[3];
    const float* M2  = (const float*)d_in[4];
    float* out = (float*)d_out;

    // zero the loss scalar (harness poisons d_out with 0xAA before every launch)
    hipMemsetAsync(out + (size_t)3 * NPIX, 0, sizeof(float), stream);

    // NPIX / (256 threads * 4 px) = 8192 blocks, exact cover
    vm_fwd<<<8192, 256, 0, stream>>>(im1, im2, C, M1, M2, out);
}

// Round 14
// 343.133 us; speedup vs baseline: 1.0706x; 1.0706x over previous
//
#include <hip/hip_runtime.h>

// ViewMorphing forward — MI355X (gfx950)
// out[0 .. 3*N*HW-1] = warped+masked image sum, out[3*N*HW] = oob loss scalar.
//
// v12 (resubmit — R13 failed on container acquisition, kernel never ran):
//      kill the spill at the source. v9-v11: reg-staged LDS staging (pf[10]
//      = 40 VGPR held across barriers) cannot fit the 64-VGPR bucket the
//      allocator insists on (waves_per_eu hint ignored) -> 82MB scratch
//      round-trip every launch. Replace staging with hardware
//      global_load_lds (width 16): no VGPR round-trip, no ds_writes.
//      Our layout already satisfies its constraint (wave-uniform LDS base +
//      lane*16B, linear unpadded stride-512 rows).
//      Pipeline per phase: issue 10 wave-loads -> __syncthreads (implicit
//      vmcnt drain) -> sample -> __syncthreads. Lost T14 overlap is covered
//      by 4-blocks/CU cross-block TLP.
//  - keeps: 10-row window (rows r-4..r+5; P(fallback)~6e-5), float2/ds_read2
//    taps, stride-512 (bank = col mod 32), consecutive-pixel mapping, XCD
//    slab swizzle, NT streams, exact reference math.

constexpr int D    = 512;
constexpr int HW   = D * D;            // 262144 = 2^18
constexpr int NB   = 32;
constexpr int NPIX = NB * HW;          // 8,388,608
// loss scale: 0.01 / (N*2*HW) / (D*D)
constexpr float LOSS_SCALE = (float)(0.01 / (2.0 * (double)NPIX * (double)HW));

constexpr int WROWS   = 10;                // rows [r-4, r+5]
constexpr int RSTRIDE = 512;               // = 0 mod 32: bank = col mod 32
constexpr int PLANE   = WROWS * RSTRIDE;   // 5120 floats per image-channel
constexpr int LDSZ    = 2 * PLANE;         // 40,960 B exactly -> 4 blocks/CU
constexpr int INLIM   = (WROWS - 1) << 9;  // in-window: rel in [0, INLIM)

__device__ __forceinline__ float lerp2(float v00, float v01, float v10, float v11,
                                       float ax, float ay)
{
    float top = fmaf(ay, v01 - v00, v00);
    float bot = fmaf(ay, v11 - v10, v10);
    return fmaf(ax, bot - top, top);
}

// async global->LDS, 16B per lane; LDS dest = wave-uniform base + lane*16
__device__ __forceinline__ void gload_lds16(const float* g, float* l)
{
    __builtin_amdgcn_global_load_lds(
        (const __attribute__((address_space(1))) void*)g,
        (__attribute__((address_space(3))) void*)l, 16, 0, 0);
}

__global__ void __launch_bounds__(256)
vm_fwd(const float* __restrict__ im1, const float* __restrict__ im2,
       const float* __restrict__ C,   const float* __restrict__ M1,
       const float* __restrict__ M2,  float* __restrict__ out)
{
    __shared__ float lds[LDSZ];

    // XCD slab swizzle (bijective: 8192 = 8*1024): XCD x owns 4 whole images.
    const int b    = blockIdx.x;
    const int slab = ((b & 7) << 10) | (b >> 3);

    const int n   = slab >> 8;
    const int k   = slab & 255;                 // row-pair index within image
    const int r   = k << 1;                     // first owned pixel row
    const int tid = threadIdx.x;
    const int hw0 = (k << 10) | tid;
    const int wlo = min(max(r - 4, 0), D - WROWS);   // staged-window first row
    const int wbase = wlo << 9;

    const float* Cn = C   + (size_t)n * 2 * HW;
    const float* Mp = M1  + (size_t)n * HW;
    const float* Mq = M2  + (size_t)n * HW;
    const float* p1 = im1 + (size_t)n * 3 * HW;
    const float* p2 = im2 + (size_t)n * 3 * HW;
    float* op       = out + (size_t)n * 3 * HW;

    // staging geometry: wave w (0..3), lane l. Each wave-call stages 256
    // consecutive floats (64 lanes x 16B): row-half (w&1), row-slot parity
    // from (w>>1); 10 calls cover 2 img x 10 rows x 512 cols.
    const int w    = tid >> 6;
    const int lane = tid & 63;
    const int half = (w & 1) << 8;              // 0 or 256 floats
    const int su   = w >> 1;                    // 0 or 1: row parity
    const int lf   = lane << 2;                 // lane float offset (x4)

    // ISSUE(ch): 10 global_load_lds per thread (wave-instr each)
    #define ISSUE(CH)                                                           \
        _Pragma("unroll")                                                       \
        for (int q = 0; q < 10; ++q) {                                          \
            const float* ip = (q < 5) ? p1 : p2;                                \
            int u = (q % 5) * 2 + su;                                           \
            gload_lds16(ip + (size_t)(CH) * HW + ((wlo + u) << 9) + half + lf,  \
                        lds + ((q < 5) ? 0 : PLANE) + u * RSTRIDE + half + lf); \
        }

    ISSUE(0);                                   // in flight during coord math

    // ---- coord precompute (once; reused across 3 channel phases) ----
    float oob = 0.0f;
    float axA[4], ayA[4], w1v[4], axB[4], ayB[4], w2v[4];
    int   offA[4], offB[4];

    #pragma unroll
    for (int j = 0; j < 4; ++j) {
        const int hw = hw0 + j * 256;
        const float qx = (float)(hw >> 9);
        const float qy = (float)(hw & 511);
        float c0 = __builtin_nontemporal_load(Cn + hw);
        float c1 = __builtin_nontemporal_load(Cn + HW + hw);
        float m1 = __builtin_nontemporal_load(Mp + hw);
        float m2 = __builtin_nontemporal_load(Mq + hw);

        const float hi = 510.999f;              // D - 1.001
        // --- A: im1 at q + c ---
        {
            float q0o = qx + c0, q1o = qy + c1;
            float q0 = fminf(fmaxf(q0o, 0.001f), hi);
            float q1 = fminf(fmaxf(q1o, 0.001f), hi);
            float d0 = q0o - q0, d1 = q1o - q1;
            oob = fmaf(d0, d0, oob); oob = fmaf(d1, d1, oob);
            float fx = floorf(q0), fy = floorf(q1);
            axA[j] = q0 - fx; ayA[j] = q1 - fy;
            // reference ceil==floor case: coincident taps, weights sum to 2
            float sc = ((axA[j] == 0.0f) ? 2.0f : 1.0f) * ((ayA[j] == 0.0f) ? 2.0f : 1.0f);
            w1v[j] = m1 * sc;
            offA[j] = (int)fy + (((int)fx) << 9);    // global flat (row-major)
        }
        // --- B: im2 at q - c ---
        {
            float q0o = qx - c0, q1o = qy - c1;
            float q0 = fminf(fmaxf(q0o, 0.001f), hi);
            float q1 = fminf(fmaxf(q1o, 0.001f), hi);
            float d0 = q0o - q0, d1 = q1o - q1;
            oob = fmaf(d0, d0, oob); oob = fmaf(d1, d1, oob);
            float fx = floorf(q0), fy = floorf(q1);
            axB[j] = q0 - fx; ayB[j] = q1 - fy;
            float sc = ((axB[j] == 0.0f) ? 2.0f : 1.0f) * ((ayB[j] == 0.0f) ? 2.0f : 1.0f);
            w2v[j] = m2 * sc;
            offB[j] = (int)fy + (((int)fx) << 9);
        }
    }

    __syncthreads();                            // drains vmcnt -> ch0 visible

    #pragma unroll
    for (int ch = 0; ch < 3; ++ch) {
        const float* g1 = p1 + (size_t)ch * HW; // fallback bases (SGPR)
        const float* g2 = p2 + (size_t)ch * HW;
        float* oc = op + (size_t)ch * HW;

        #pragma unroll
        for (int j = 0; j < 4; ++j) {
            float ra, rb;
            int relA = offA[j] - wbase;         // = u*512 + iy when in-window
            if ((unsigned)relA < (unsigned)INLIM) {
                float2 t0, t1;                  // adjacent cols -> ds_read2_b32
                __builtin_memcpy(&t0, &lds[relA], 8);
                __builtin_memcpy(&t1, &lds[relA + RSTRIDE], 8);
                ra = lerp2(t0.x, t0.y, t1.x, t1.y, axA[j], ayA[j]);
            } else {
                const float* pa = g1 + offA[j];
                ra = lerp2(pa[0], pa[1], pa[512], pa[513], axA[j], ayA[j]);
            }
            int relB = offB[j] - wbase;
            if ((unsigned)relB < (unsigned)INLIM) {
                float2 t0, t1;
                __builtin_memcpy(&t0, &lds[PLANE + relB], 8);
                __builtin_memcpy(&t1, &lds[PLANE + relB + RSTRIDE], 8);
                rb = lerp2(t0.x, t0.y, t1.x, t1.y, axB[j], ayB[j]);
            } else {
                const float* pb = g2 + offB[j];
                rb = lerp2(pb[0], pb[1], pb[512], pb[513], axB[j], ayB[j]);
            }
            __builtin_nontemporal_store(fmaf(ra, w1v[j], rb * w2v[j]),
                                        oc + hw0 + j * 256);
        }
        __syncthreads();                        // all reads of this ch done
        if (ch < 2) {
            ISSUE(ch + 1);                      // overwrite staged buffer
            __syncthreads();                    // drain -> next ch visible
        }
    }

    // block-level reduction of oob; reuses lds (all staged reads done)
    #pragma unroll
    for (int off = 32; off > 0; off >>= 1)
        oob += __shfl_down(oob, off, 64);

    if (lane == 0) lds[w] = oob;
    __syncthreads();
    if (tid == 0) {
        float s = lds[0] + lds[1] + lds[2] + lds[3];
        atomicAdd(out + (size_t)3 * NPIX, s * LOSS_SCALE);
    }
}

extern "C" void kernel_launch(void* const* d_in, const int* in_sizes, int n_in,
                              void* d_out, int out_size, void* d_ws, size_t ws_size,
                              hipStream_t stream) {
    const float* im1 = (const float*)d_in[0];
    const float* im2 = (const float*)d_in[1];
    const float* C   = (const float*)d_in[2];
    const float* M1  = (const float*)d_in[3];
    const float* M2  = (const float*)d_in[4];
    float* out = (float*)d_out;

    // zero the loss scalar (harness poisons d_out with 0xAA before every launch)
    hipMemsetAsync(out + (size_t)3 * NPIX, 0, sizeof(float), stream);

    // NPIX / (256 threads * 4 px) = 8192 blocks, exact cover
    vm_fwd<<<8192, 256, 0, stream>>>(im1, im2, C, M1, M2, out);
}